// Round 9
// baseline (189.110 us; speedup 1.0000x reference)
//
#include <hip/hip_runtime.h>

#define IMG    384
#define IMG4   96
#define IMG2   (IMG*IMG)
#define CROP   378
#define NB     64
#define NGRP   8
#define NROWS  48      // crop rows per block
#define SPB    12      // stripes (4 rows each)
#define NTH    896     // 14 waves = 7 shifts x 2 row-halves
#define PSTR   424     // floats per (b,grp) record

__device__ __forceinline__ float wave_sum_f(float v) {
    v += __shfl_down(v, 32);
    v += __shfl_down(v, 16);
    v += __shfl_down(v, 8);
    v += __shfl_down(v, 4);
    v += __shfl_down(v, 2);
    v += __shfl_down(v, 1);
    return v;
}

__device__ __forceinline__ void dec4(unsigned u, float* d) {
    d[0] = (float)( u         & 255u);
    d[1] = (float)((u >>  8)  & 255u);
    d[2] = (float)((u >> 16)  & 255u);
    d[3] = (float)((u >> 24)  & 255u);
}

// Planar LDS: f4-col c lives at [part=c%3][slot=c/3]; window reads are dense
// consecutive ds_read_b128 per part-plane (conflict-free). Staging WRITES are
// made dense by swizzling the GLOBAL source: staging thread t writes LDS slot
// [ (t%96)/32 ][ t%32 ] and loads global f4-col c = 3*(t%32) + (t%96)/32.
// 16-row circular buffer: stripe s reads local rows [4s,4s+9], stages
// [4s+10,4s+13] (disjoint mod 16) -> single barrier per stripe.
// __launch_bounds__(NTH, 1): request MINIMUM occupancy so the backend caps
// VGPR at the launchability bound (512/4 = 128), not an occupancy-tuned 64.
// R6/R8 lesson: a 64-VGPR cap spills ~100-reg live set -> 300+ MB scratch.
__global__ __launch_bounds__(NTH, 1)
void corr_kernel(const float* __restrict__ sr, const float* __restrict__ hr,
                 const float* __restrict__ mk, float* __restrict__ part)
{
    __shared__ float4   lq [16][3][32];   // 24576 B, q = hr*mask
    __shared__ unsigned lmb[16][3][32];   //  6144 B, mask bytes
    __shared__ float    wbuf[14][26];     //  1456 B, reduction

    const int tid = threadIdx.x;
    // XCD-clustered: all 8 blocks of a batch on one XCD class
    const int id  = blockIdx.x;
    const int c8  = id & 7;
    const int k0  = id >> 3;                 // 0..63
    const int b   = c8 + 8 * (k0 >> 3);
    const int grp = k0 & 7;
    const int c0  = grp * NROWS;
    const int vrows = (CROP - c0 < NROWS) ? (CROP - c0) : NROWS;

    const float4* sb4 = (const float4*)(sr + (size_t)b * IMG2);
    const float4* hb4 = (const float4*)(hr + (size_t)b * IMG2);
    const float4* mb4 = (const float4*)(mk + (size_t)b * IMG2);

    const int wid  = tid >> 6;        // 0..13
    const int lane = tid & 63;
    const int w    = wid % 7;         // row shift i
    const int h    = wid / 7;         // row-half within stripe
    const int l    = lane & 31;       // 12-px chunk (cols 12l..12l+11)
    const int rsel = lane >> 5;       // row within half
    const int l1   = (l + 1) & 31;    // wrap: only meets zeroed pe terms

    // staging map (tid < 384): LDS-dense slot, swizzled global col
    const int sli  = tid % 96;
    const int ssub = tid / 96;        // new-row index 0..3
    const int spt  = sli / 32;
    const int ssl  = sli % 32;
    const int scg  = 3 * ssl + spt;   // global f4-col

    // edge map: lanes 0..11 of h=1 waves handle cols {0..5,378..383}, shift w
    const int ecol = (lane < 6) ? lane : (372 + lane);   // lane 6..11 -> 378..383
    const int ecf  = ecol >> 2;
    const int ept  = ecf % 3;
    const int esl  = ecf / 3;
    const int esub = ecol & 3;

    float aA[7] = {0,0,0,0,0,0,0};
    float aB[7] = {0,0,0,0,0,0,0};
    float aC[7] = {0,0,0,0,0,0,0};
    float aTm = 0.f, aTq = 0.f, aTq2 = 0.f, aSp = 0.f;
    float eM = 0.f, eQ = 0.f, eQ2 = 0.f;

    float4 sA[4];                     // sr prefetch regs (own row)
    auto prefetch_sr = [&](int s) {
        const int lr = 4 * s + 2 * h + rsel;
        // clamp to 380: keeps the +3 f4 over-read in-bounds even at l=31
        // (380*96+96 = 36576 < 36864); clamped rows fail lr<vrows and are unused.
        int ir = c0 + lr + 3; if (ir > 380) ir = 380;
        const size_t so = (size_t)ir * IMG4 + 3 * l;
        sA[0] = sb4[so];     sA[1] = sb4[so + 1];
        sA[2] = sb4[so + 2]; sA[3] = sb4[so + 3];
    };

    // ---- prologue: stage local rows 0..9 (dense LDS writes) ----
    for (int idx = tid; idx < 960; idx += NTH) {
        const int lr = idx / 96, li = idx % 96;
        const int pt = li / 32, sl = li % 32;
        const int c  = 3 * sl + pt;
        int ir = c0 + lr; if (ir > IMG - 1) ir = IMG - 1;
        const float4 hv = hb4[(size_t)ir * IMG4 + c];
        const float4 mv = mb4[(size_t)ir * IMG4 + c];
        lq [lr & 15][pt][sl] = make_float4(hv.x*mv.x, hv.y*mv.y, hv.z*mv.z, hv.w*mv.w);
        lmb[lr & 15][pt][sl] = (mv.x != 0.f ? 1u : 0u)
                             | (mv.y != 0.f ? 0x100u : 0u)
                             | (mv.z != 0.f ? 0x10000u : 0u)
                             | (mv.w != 0.f ? 0x1000000u : 0u);
    }
    prefetch_sr(0);
    __syncthreads();

    for (int s = 0; s < SPB; ++s) {
        const int lr = 4 * s + 2 * h + rsel;     // this thread's crop row

        // ---- consume sr regs -> pe/p2 (mask from LDS row lr+3) ----
        float pe[12], p2[12];
        {
            const int ms = (lr + 3) & 15;
            const unsigned w0 = lmb[ms][0][l], w1 = lmb[ms][1][l];
            const unsigned w2 = lmb[ms][2][l], w3 = lmb[ms][0][l1];
            float mcf[16];
            dec4(w0, mcf); dec4(w1, mcf + 4); dec4(w2, mcf + 8); dec4(w3, mcf + 12);
            const float sf[16] = {sA[0].x,sA[0].y,sA[0].z,sA[0].w,
                                  sA[1].x,sA[1].y,sA[1].z,sA[1].w,
                                  sA[2].x,sA[2].y,sA[2].z,sA[2].w,
                                  sA[3].x,sA[3].y,sA[3].z,sA[3].w};
            #pragma unroll
            for (int t = 0; t < 12; ++t) pe[t] = sf[t + 3] * mcf[t + 3];
            if (l == 31) {
                pe[6] = 0.f; pe[7] = 0.f; pe[8]  = 0.f;
                pe[9] = 0.f; pe[10] = 0.f; pe[11] = 0.f;
            }
            #pragma unroll
            for (int t = 0; t < 12; ++t) p2[t] = pe[t] * pe[t];
        }

        // ---- issue next-stripe global loads early ----
        float4 ph = make_float4(0,0,0,0), pm = make_float4(0,0,0,0);
        const bool doStage = (tid < 384) && (s < SPB - 1);
        const int  slr = 4 * s + 10 + ssub;
        if (doStage) {
            int ir = c0 + slr; if (ir > IMG - 1) ir = IMG - 1;
            ph = hb4[(size_t)ir * IMG4 + scg];
            pm = mb4[(size_t)ir * IMG4 + scg];
        }
        if (s < SPB - 1) prefetch_sr(s + 1);     // sA free (pe extracted)

        // ---- compute: own row, shift w ----
        if (lr < vrows) {
            const int qs = (lr + w) & 15;
            const float4 Q0 = lq[qs][0][l];
            const float4 Q1 = lq[qs][1][l];
            const float4 Q2 = lq[qs][2][l];
            const float4 Q3 = lq[qs][0][l1];
            const float4 Q4 = lq[qs][1][l1];
            const unsigned u0 = lmb[qs][0][l];
            const unsigned u1 = lmb[qs][1][l];
            const unsigned u2 = lmb[qs][2][l];
            const unsigned u3 = lmb[qs][0][l1];
            const unsigned u4 = lmb[qs][1][l1];
            const float qf[20] = {Q0.x,Q0.y,Q0.z,Q0.w, Q1.x,Q1.y,Q1.z,Q1.w,
                                  Q2.x,Q2.y,Q2.z,Q2.w, Q3.x,Q3.y,Q3.z,Q3.w,
                                  Q4.x,Q4.y,Q4.z,Q4.w};
            float mf[20];
            dec4(u0, mf); dec4(u1, mf + 4); dec4(u2, mf + 8);
            dec4(u3, mf + 12); dec4(u4, mf + 16);
            // lane 31's qf/mf[12..19] wrap to slot 0 (finite garbage) and only
            // meet pe/p2 entries that were zeroed.

            aTm += (float)(__popc(u0) + __popc(u1) + __popc(u2));
            #pragma unroll
            for (int t = 0; t < 12; ++t) {
                aTq += qf[t];
                aTq2 = fmaf(qf[t], qf[t], aTq2);
            }
            if (w == 0) {
                #pragma unroll
                for (int t = 0; t < 12; ++t) aSp += pe[t];
            }
            #pragma unroll
            for (int t = 0; t < 12; ++t) {
                const float p = pe[t], pp = p2[t];
                #pragma unroll
                for (int j = 0; j < 7; ++j) {
                    aA[j] = fmaf(p,  qf[t + j], aA[j]);
                    aB[j] = fmaf(pp, mf[t + j], aB[j]);
                    aC[j] = fmaf(p,  mf[t + j], aC[j]);
                }
            }
        }

        // ---- edge cols: lanes 0..11 of h=1 waves, own shift w ----
        if (h == 1 && lane < 12) {
            #pragma unroll
            for (int y = 0; y < 4; ++y) {
                const int elr = 4 * s + y;
                if (elr < vrows) {
                    const int qs2 = (elr + w) & 15;
                    const float qv = ((const float*)&lq[qs2][ept][esl])[esub];
                    const float mv = (float)((lmb[qs2][ept][esl] >> (8 * esub)) & 255u);
                    eM += mv;
                    eQ += qv;
                    eQ2 = fmaf(qv, qv, eQ2);
                }
            }
        }

        // ---- write-late stage (dense LDS write) ----
        if (doStage) {
            lq [slr & 15][spt][ssl] = make_float4(ph.x*pm.x, ph.y*pm.y, ph.z*pm.z, ph.w*pm.w);
            lmb[slr & 15][spt][ssl] = (pm.x != 0.f ? 1u : 0u)
                                    | (pm.y != 0.f ? 0x100u : 0u)
                                    | (pm.z != 0.f ? 0x10000u : 0u)
                                    | (pm.w != 0.f ? 0x1000000u : 0u);
        }
        __syncthreads();     // single barrier per stripe
    }

    // ---- reduction: per-wave butterflies, cross-half combine via LDS ----
    float vals[24];
    #pragma unroll
    for (int j = 0; j < 7; ++j) { vals[j] = aA[j]; vals[7+j] = aB[j]; vals[14+j] = aC[j]; }
    vals[21] = aTm; vals[22] = aTq; vals[23] = aTq2;
    #pragma unroll
    for (int k = 0; k < 24; ++k) {
        const float v = wave_sum_f(vals[k]);
        if (lane == 0) wbuf[wid][k] = v;
    }
    {
        const float sp = wave_sum_f(aSp);
        if (w == 0 && lane == 0) wbuf[wid][24] = sp;   // waves 0 and 7
    }
    __syncthreads();

    float* po = part + ((size_t)b * NGRP + grp) * PSTR;
    if (tid < 168) {
        const int w2 = tid / 24, k = tid % 24;
        const float v = wbuf[w2][k] + wbuf[w2 + 7][k];
        int off;
        if      (k <  7) off = w2*7 + k;              // A[i][j]
        else if (k < 14) off = 49 + w2*7 + (k-7);     // B
        else if (k < 21) off = 98 + w2*7 + (k-14);    // C
        else if (k == 21) off = 147 + w2;             // Tm(i)
        else if (k == 22) off = 154 + w2;             // Tq(i)
        else              off = 161 + w2;             // Tq2(i)
        po[off] = v;
    }
    if (tid == 168) po[168] = wbuf[0][24] + wbuf[7][24];
    if (h == 1 && lane < 12) {
        po[169 + w*12 + lane] = eM;
        po[253 + w*12 + lane] = eQ;
        po[337 + w*12 + lane] = eQ2;
    }
}

__global__ __launch_bounds__(64)
void mse_kernel(const float* __restrict__ part, double* __restrict__ bmin)
{
    const int b = blockIdx.x;
    const int s = threadIdx.x;           // shifts 0..48 active
    double mse = 1e300;
    if (s < 49) {
        const int i = s / 7, j = s % 7;
        double A=0, Bc=0, Cc=0, Tm=0, Tq=0, Tq2=0, Sp=0;
        for (int g = 0; g < NGRP; ++g) {
            const float* p = part + ((size_t)b * NGRP + g) * PSTR;
            A  += p[      i*7 + j];
            Bc += p[ 49 + i*7 + j];
            Cc += p[ 98 + i*7 + j];
            Tm += p[147 + i];
            Tq += p[154 + i];
            Tq2+= p[161 + i];
            Sp += p[168];
            #pragma unroll
            for (int t = 0; t < 12; ++t) {
                if (t < j || t >= j + 6) {   // col outside x-window [j, j+377]
                    Tm  -= p[169 + i*12 + t];
                    Tq  -= p[253 + i*12 + t];
                    Tq2 -= p[337 + i*12 + t];
                }
            }
        }
        const double bb = (Tq - Sp) / Tm;
        mse = (Tq2 - 2.0*A - 2.0*bb*Tq + Bc + 2.0*bb*Cc + bb*bb*Tm) / Tm;
    }
    for (int off = 32; off; off >>= 1) {
        const double o = __shfl_down(mse, off);
        mse = fmin(mse, o);
    }
    if (s == 0) bmin[b] = mse;
}

__global__ __launch_bounds__(64)
void mean_kernel(const double* __restrict__ bmin, float* __restrict__ out)
{
    double v = bmin[threadIdx.x];
    for (int off = 32; off; off >>= 1) v += __shfl_down(v, off);
    if (threadIdx.x == 0) out[0] = (float)(v / 64.0);
}

extern "C" void kernel_launch(void* const* d_in, const int* in_sizes, int n_in,
                              void* d_out, int out_size, void* d_ws, size_t ws_size,
                              hipStream_t stream) {
    const float* sr = (const float*)d_in[0];
    const float* hr = (const float*)d_in[1];
    const float* mk = (const float*)d_in[2];

    float* part = (float*)d_ws;
    const size_t part_bytes = (size_t)NB * NGRP * PSTR * sizeof(float);  // 868352
    double* bmin = (double*)((char*)d_ws + part_bytes);

    corr_kernel<<<dim3(NB * NGRP), NTH, 0, stream>>>(sr, hr, mk, part);
    mse_kernel<<<dim3(NB), 64, 0, stream>>>(part, bmin);
    mean_kernel<<<dim3(1), 64, 0, stream>>>(bmin, (float*)d_out);
}

// Round 10
// 73.948 us; speedup vs baseline: 2.5573x; 2.5573x over previous
//
#include <hip/hip_runtime.h>

#define IMG   384
#define IMG4  96
#define IMG2  (IMG*IMG)
#define CROP  378
#define NB    64
#define NGRP  8
#define NROWS 48
#define NSTR  24          // stripes of 2 crop rows
#define NTH   256
#define PSTR  520         // 256 D + 8 D2 + 252 edges + pad

typedef __fp16 half8  __attribute__((ext_vector_type(8)));
typedef __fp16 f16x2  __attribute__((ext_vector_type(2)));
typedef float  floatx4 __attribute__((ext_vector_type(4)));

__device__ __forceinline__ unsigned pkh(float a, float b) {
    f16x2 h = __builtin_amdgcn_cvt_pkrtz(a, b);
    return __builtin_bit_cast(unsigned, h);
}

// MFMA formulation: one 16x16x32 f16 MFMA per (crop-row r, 32-wide u-slice)
//   A rows  0..6  = q[r+i][u]      (i = row shift)      7..13 = mask[r+i][u]
//           14    = ones           15 = zero
//   B cols  0..6  = p[r][u-j]      (j = col shift)      7..13 = p^2[r][u-j]
//           14    = ones           15 = zero
//   D[i][j]=A, D[7+i][j]=C, D[7+i][7+j]=B, D[i][14]=Tq(i), D[7+i][14]=Tm(i),
//   D[14][0]=Sp.   Second MFMA (A2 = q^2 rows, same B): D2[i][14]=Tq2(i).
// k-sum is permutation-invariant: A and B fragments use the HW's identical
// (lane-group, elem)->k map, so per-lane "8 contiguous elements" packing is
// correct regardless of the internal k order. C/D layout is the HW-verified
// col=lane&15, row=(lane>>4)*4+reg.
// LDS planes f16: q/m/q2 [16 rows][392] (784B pitch, 16B-mult, 196dw%32=4 ->
// A-frag row reads are 2-way-free). p/p2 [8 rows][400] (800B, PAD=8 elems:
// x = v+8; B-frag byte S = 64*sl+16g+16-2j, 4-aligned floor + alignbit).
__global__ __launch_bounds__(NTH)
void corr_kernel(const float* __restrict__ sr, const float* __restrict__ hr,
                 const float* __restrict__ mk, float* __restrict__ part)
{
    __shared__ __align__(16) char qpl [16*784];
    __shared__ __align__(16) char mpl [16*784];
    __shared__ __align__(16) char q2pl[16*784];
    __shared__ __align__(16) char ppl [8*800];
    __shared__ __align__(16) char p2pl[8*800];
    __shared__ __align__(16) char ones[800];
    __shared__ __align__(16) char zrow[800];
    __shared__ float wred[4][256];
    __shared__ float d2red[4][8];

    const int tid = threadIdx.x;
    // XCD-clustered: all 8 blocks of a batch on one XCD class
    const int id  = blockIdx.x;
    const int c8  = id & 7;
    const int k0  = id >> 3;
    const int b   = c8 + 8 * (k0 >> 3);
    const int grp = k0 & 7;
    const int c0  = grp * NROWS;          // multiple of 16 (48*g)

    const float*  sb  = sr + (size_t)b * IMG2;
    const float4* hb4 = (const float4*)(hr + (size_t)b * IMG2);
    const float4* mb4 = (const float4*)(mk + (size_t)b * IMG2);

    const int wid  = tid >> 6;            // 0..3
    const int lane = tid & 63;
    const int m16  = lane & 15;
    const int g    = lane >> 4;

    floatx4 D  = {0.f, 0.f, 0.f, 0.f};
    floatx4 D2 = {0.f, 0.f, 0.f, 0.f};

    // edge slot: thread (i, t, kind) accumulates plane value at edge col
    float eacc = 0.f;
    int ei = 0, et = 0, ek = 0, ecolByte = 0;
    if (tid < 252) {
        ei = tid / 36; const int rem = tid % 36; et = rem % 12; ek = rem / 12;
        const int ec = (et < 6) ? et : (372 + et);
        ecolByte = 2 * ec;
    }

    auto stage_qm = [&](int relBase, int nrows) {
        for (int idx = tid; idx < nrows * 96; idx += NTH) {
            const int rw = idx / 96, c = idx % 96;
            const int rel = relBase + rw;
            int w = c0 + rel; if (w > 383) w = 383;       // clamp load only
            const float4 hv = hb4[(size_t)w * IMG4 + c];
            const float4 mv = mb4[(size_t)w * IMG4 + c];
            const float qx = hv.x*mv.x, qy = hv.y*mv.y;
            const float qz = hv.z*mv.z, qw = hv.w*mv.w;
            const int slot = rel & 15;
            *(uint2*)(qpl  + slot*784 + c*8) = make_uint2(pkh(qx, qy), pkh(qz, qw));
            *(uint2*)(mpl  + slot*784 + c*8) = make_uint2(pkh(mv.x, mv.y), pkh(mv.z, mv.w));
            *(uint2*)(q2pl + slot*784 + c*8) = make_uint2(pkh(qx*qx, qy*qy), pkh(qz*qz, qw*qw));
        }
    };
    auto stage_p = [&](int relBase) {   // two p-rows relBase, relBase+1
        for (int idx = tid; idx < 2*189; idx += NTH) {
            const int rw = idx / 189, d = 4 + idx % 189;  // x-dwords 4..192
            const int rrel = relBase + rw;
            int rq = c0 + rrel; if (rq > 377) rq = 377;   // clamp load only
            const int v0 = 2*d - 8;                       // v pair v0, v0+1
            const float* srow = sb + (size_t)(rq + 3) * IMG + (v0 + 3);
            const float s0 = srow[0], s1 = srow[1];
            const int ms = (rq + 3) & 15;                 // mask row in q/m circ
            const float mf0 = (float)*(const __fp16*)(mpl + ms*784 + 4*d - 10);
            const float mf1 = (float)*(const __fp16*)(mpl + ms*784 + 4*d - 8);
            const float p0 = s0 * mf0, p1 = s1 * mf1;
            const int slot = rrel & 7;
            *(unsigned*)(ppl  + slot*800 + 4*d) = pkh(p0, p1);
            *(unsigned*)(p2pl + slot*800 + 4*d) = pkh(p0*p0, p1*p1);
        }
    };

    // ---- prologue: constants, pads, q/m/q2 rows 0..7, p rows 0..1 ----
    for (int dd = tid; dd < 200; dd += NTH) {
        ((unsigned*)ones)[dd] = (dd >= 4 && dd < 196) ? 0x3C003C00u : 0u;
        ((unsigned*)zrow)[dd] = 0u;
    }
    for (int idx = tid; idx < 8*2*11; idx += NTH) {      // p-plane pad dwords
        const int slot = idx / 22, rem = idx % 22;
        const int pl = rem / 11, k = rem % 11;
        const int dd = (k < 4) ? k : (189 + k);          // 0..3, 193..199
        *(unsigned*)((pl ? p2pl : ppl) + slot*800 + 4*dd) = 0u;
    }
    stage_qm(0, 8);
    __syncthreads();
    stage_p(0);
    __syncthreads();

    // ---- main loop: stripe = 2 crop rows; reads rows [2s..2s+7] (q/m) and
    //      [2s,2s+1] (p); writes rows [2s+8,2s+9] (q/m), [2s+2,2s+3] (p) —
    //      disjoint mod 16 / mod 8 -> single barrier per stripe ----
    for (int s = 0; s < NSTR; ++s) {
        const int r = c0 + 2*s + (wid & 1);
        if (r <= 377) {
            const int mm    = (m16 < 7) ? m16 : (m16 - 7);
            const int slotA = (2*s + (wid & 1) + mm) & 15;
            const char* aB; const char* bB; int j;
            if (m16 < 7)        { aB = qpl + slotA*784; bB = ppl  + (r & 7)*800; j = m16; }
            else if (m16 < 14)  { aB = mpl + slotA*784; bB = p2pl + (r & 7)*800; j = m16 - 7; }
            else if (m16 == 14) { aB = ones + 16;       bB = ones;               j = 0; }
            else                { aB = zrow;            bB = zrow;               j = 0; }
            const char* a2B = (m16 < 7) ? (q2pl + slotA*784) : aB;
            const int Sb  = 16 - 2*j + g*16;
            const int sl0 = 6 * (wid >> 1);
            #pragma unroll
            for (int t2 = 0; t2 < 6; ++t2) {
                const int sl  = sl0 + t2;
                const int off = sl*64 + g*16;
                const half8 av  = *(const half8*)(aB  + off);
                const half8 a2v = *(const half8*)(a2B + off);
                const int S  = Sb + sl*64;
                const int S0 = S & ~3;
                const unsigned sh = (unsigned)((S & 2) << 3);
                const unsigned* bw = (const unsigned*)(bB + S0);
                const unsigned d0 = bw[0], d1 = bw[1], d2 = bw[2], d3 = bw[3], d4 = bw[4];
                uint4 bi;
                bi.x = __builtin_amdgcn_alignbit(d1, d0, sh);
                bi.y = __builtin_amdgcn_alignbit(d2, d1, sh);
                bi.z = __builtin_amdgcn_alignbit(d3, d2, sh);
                bi.w = __builtin_amdgcn_alignbit(d4, d3, sh);
                const half8 bv = __builtin_bit_cast(half8, bi);
                D  = __builtin_amdgcn_mfma_f32_16x16x32_f16(av,  bv, D,  0, 0, 0);
                D2 = __builtin_amdgcn_mfma_f32_16x16x32_f16(a2v, bv, D2, 0, 0, 0);
            }
        }

        // edges: window rows (c0+2s+i), (c0+2s+1+i) for valid crop rows
        if (tid < 252) {
            #pragma unroll
            for (int rr = 0; rr < 2; ++rr) {
                if (c0 + 2*s + rr <= 377) {
                    const int slot = (2*s + rr + ei) & 15;
                    const char* pl = (ek == 0) ? mpl : qpl;
                    const float v = (float)*(const __fp16*)(pl + slot*784 + ecolByte);
                    eacc += (ek == 2) ? v*v : v;
                }
            }
        }

        stage_qm(2*s + 8, 2);
        stage_p(2*s + 2);
        __syncthreads();
    }

    // ---- reduce 4 waves' D/D2, write record ----
    {
        const int rb = (lane >> 4) * 4, col = lane & 15;
        #pragma unroll
        for (int k = 0; k < 4; ++k)
            wred[wid][(rb + k)*16 + col] = D[k];
        #pragma unroll
        for (int k = 0; k < 4; ++k) {
            const int row = rb + k;
            if (col == 14 && row < 8) d2red[wid][row] = D2[k];
        }
    }
    __syncthreads();
    float* po = part + (size_t)(b * NGRP + grp) * PSTR;
    po[tid] = wred[0][tid] + wred[1][tid] + wred[2][tid] + wred[3][tid];
    if (tid < 8)
        po[256 + tid] = d2red[0][tid] + d2red[1][tid] + d2red[2][tid] + d2red[3][tid];
    if (tid < 252)
        po[264 + ek*84 + ei*12 + et] = eacc;
}

__global__ __launch_bounds__(64)
void mse_kernel(const float* __restrict__ part, double* __restrict__ bmin)
{
    const int b = blockIdx.x;
    const int s = threadIdx.x;           // shifts 0..48 active
    double mse = 1e300;
    if (s < 49) {
        const int i = s / 7, j = s % 7;
        double A=0, Bc=0, Cc=0, Tm=0, Tq=0, Tq2=0, Sp=0;
        double colm[12]={0}, colq[12]={0}, colq2[12]={0};
        for (int gg = 0; gg < NGRP; ++gg) {
            const float* p = part + (size_t)(b * NGRP + gg) * PSTR;
            A   += p[i*16 + j];
            Cc  += p[(7+i)*16 + j];
            Bc  += p[(7+i)*16 + 7 + j];
            Tq  += p[i*16 + 14];
            Tm  += p[(7+i)*16 + 14];
            Sp  += p[14*16 + 0];
            Tq2 += p[256 + i];
            #pragma unroll
            for (int t = 0; t < 12; ++t) {
                colm[t]  += p[264 +      i*12 + t];
                colq[t]  += p[264 + 84 + i*12 + t];
                colq2[t] += p[264 +168 + i*12 + t];
            }
        }
        #pragma unroll
        for (int t = 0; t < 12; ++t) {
            if (t < j || t >= j + 6) {   // col outside x-window [j, j+377]
                Tm -= colm[t]; Tq -= colq[t]; Tq2 -= colq2[t];
            }
        }
        const double bb = (Tq - Sp) / Tm;
        mse = (Tq2 - 2.0*A - 2.0*bb*Tq + Bc + 2.0*bb*Cc + bb*bb*Tm) / Tm;
    }
    for (int off = 32; off; off >>= 1) {
        const double o = __shfl_down(mse, off);
        mse = fmin(mse, o);
    }
    if (s == 0) bmin[b] = mse;
}

__global__ __launch_bounds__(64)
void mean_kernel(const double* __restrict__ bmin, float* __restrict__ out)
{
    double v = bmin[threadIdx.x];
    for (int off = 32; off; off >>= 1) v += __shfl_down(v, off);
    if (threadIdx.x == 0) out[0] = (float)(v / 64.0);
}

extern "C" void kernel_launch(void* const* d_in, const int* in_sizes, int n_in,
                              void* d_out, int out_size, void* d_ws, size_t ws_size,
                              hipStream_t stream) {
    const float* sr = (const float*)d_in[0];
    const float* hr = (const float*)d_in[1];
    const float* mk = (const float*)d_in[2];

    float* part = (float*)d_ws;
    const size_t part_bytes = (size_t)NB * NGRP * PSTR * sizeof(float); // 1064960
    double* bmin = (double*)((char*)d_ws + part_bytes);

    corr_kernel<<<dim3(NB * NGRP), NTH, 0, stream>>>(sr, hr, mk, part);
    mse_kernel<<<dim3(NB), 64, 0, stream>>>(part, bmin);
    mean_kernel<<<dim3(1), 64, 0, stream>>>(bmin, (float*)d_out);
}

// Round 11
// 70.778 us; speedup vs baseline: 2.6719x; 1.0448x over previous
//
#include <hip/hip_runtime.h>

#define IMG   384
#define IMG4  96
#define IMG2  (IMG*IMG)
#define CROP  378
#define NB    64
#define NGRP  12
#define NROWS 32
#define NSTR  8           // stripes of 4 crop rows
#define NTH   256
#define PSTR  520         // 256 D + 8 Tq2 + 252 edges + pad

typedef __fp16 half8  __attribute__((ext_vector_type(8)));
typedef __fp16 f16x2  __attribute__((ext_vector_type(2)));
typedef float  floatx4 __attribute__((ext_vector_type(4)));

__device__ __forceinline__ unsigned pkh(float a, float b) {
    f16x2 h = __builtin_amdgcn_cvt_pkrtz(a, b);
    return __builtin_bit_cast(unsigned, h);
}
__device__ __forceinline__ int mod20(int x) {   // valid for x in [0, 60)
    x -= (x >= 20) ? 20 : 0;
    x -= (x >= 20) ? 20 : 0;
    return x;
}

// MFMA formulation (verified R10): one 16x16x32 f16 MFMA per (crop-row r,
// 32-wide u-slice):
//   A rows 0..6 = q[r+i][u], 7..13 = mask[r+i][u], 14 = ones, 15 = zero
//   B cols 0..6 = p[r][u-j], 7..13 = p^2[r][u-j], 14 = ones, 15 = zero
//   D[i][j]=A, D[7+i][j]=C, D[7+i][7+j]=B, D[i][14]=Tq(i), D[7+i][14]=Tm(i),
//   D[14][0]=Sp.  Tq2(i) comes from f32 per-row q^2 sums (rowQ2) instead of a
//   second MFMA (R11: halves MFMA + LDS-read traffic).
// k-sum is permutation-invariant (A and B share the HW (lane-group,elem)->k
// map); C/D layout is the HW-verified col=lane&15, row=(lane>>4)*4+reg.
// Circular buffers: q/m 20 rows (784B pitch); p/p2 8 rows (800B pitch, PAD=8
// elems so B byte S = 64*sl + 16g + 16 - 2j; aligned floor + v_alignbit).
// Stripe s: compute rows 4s..4s+3 (wave wid = row), reads q rels [4s..4s+9],
// p rels [4s..4s+3]; stages qm rels [4s+14..4s+17] (disjoint mod 20), p rels
// [4s+4..4s+7] (mask need rels <= 4s+10 <= staged 4(s-1)+17, race-free;
// disjoint mod 8) -> single barrier per stripe.
__global__ __launch_bounds__(NTH)
void corr_kernel(const float* __restrict__ sr, const float* __restrict__ hr,
                 const float* __restrict__ mk, float* __restrict__ part)
{
    __shared__ __align__(16) char qpl [20*784];
    __shared__ __align__(16) char mpl [20*784];
    __shared__ __align__(16) char ppool[2*8*800 + 16];  // p2 staggered +16B
    __shared__ __align__(16) char ones[800];
    __shared__ __align__(16) char zrow[800];
    __shared__ float wred[4][256];
    __shared__ float rowQ2[44];
    char* const ppl  = ppool;
    char* const p2pl = ppool + 8*800 + 16;

    const int tid = threadIdx.x;
    // XCD-clustered: all 12 blocks of a batch on one XCD class
    const int id  = blockIdx.x;
    const int c8  = id & 7;
    const int k0  = id >> 3;              // 0..95
    const int b   = c8 + 8 * (k0 / NGRP);
    const int grp = k0 % NGRP;
    const int c0  = grp * NROWS;          // multiple of 32
    const int nvalid = (CROP - c0 < NROWS) ? (CROP - c0) : NROWS;

    const float*  sb  = sr + (size_t)b * IMG2;
    const float4* hb4 = (const float4*)(hr + (size_t)b * IMG2);
    const float4* mb4 = (const float4*)(mk + (size_t)b * IMG2);

    const int wid  = tid >> 6;            // 0..3 = row within stripe
    const int lane = tid & 63;
    const int m16  = lane & 15;
    const int g    = lane >> 4;

    floatx4 D = {0.f, 0.f, 0.f, 0.f};

    // edge slot: thread (i, t, kind) accumulates plane value at edge col
    float eacc = 0.f;
    int ei = 0, et = 0, ek = 0, ecolByte = 0;
    if (tid < 252) {
        ei = tid / 36; const int rem = tid % 36; et = rem % 12; ek = rem / 12;
        const int ec = (et < 6) ? et : (372 + et);
        ecolByte = 2 * ec;
    }

    auto stage_qm = [&](int relBase, int nrows) {
        for (int idx = tid; idx < nrows * 96; idx += NTH) {
            const int rw = idx / 96, c = idx % 96;
            const int rel = relBase + rw;
            int w = c0 + rel; if (w > 383) w = 383;       // clamp load only
            const float4 hv = hb4[(size_t)w * IMG4 + c];
            const float4 mv = mb4[(size_t)w * IMG4 + c];
            const float qx = hv.x*mv.x, qy = hv.y*mv.y;
            const float qz = hv.z*mv.z, qw = hv.w*mv.w;
            const int slot = mod20(rel);
            *(uint2*)(qpl + slot*784 + c*8) = make_uint2(pkh(qx, qy), pkh(qz, qw));
            *(uint2*)(mpl + slot*784 + c*8) = make_uint2(pkh(mv.x, mv.y), pkh(mv.z, mv.w));
            atomicAdd(&rowQ2[rel], qx*qx + qy*qy + qz*qz + qw*qw);
        }
    };
    auto stage_p = [&](int relBase) {     // four p-rows relBase..relBase+3
        for (int idx = tid; idx < 4*189; idx += NTH) {
            const int rw = idx / 189, d = 4 + idx % 189;  // x-dwords 4..192
            const int rrel = relBase + rw;
            int rc = rrel; if (c0 + rc > 377) rc = 377 - c0;  // rel clamp
            const int v0 = 2*d - 8;                       // pixel pair v0, v0+1
            const float* srow = sb + (size_t)(c0 + rc + 3) * IMG + (v0 + 3);
            const float s0 = srow[0], s1 = srow[1];
            const int ms = mod20(rc + 3);                 // mask row (staged)
            const float mf0 = (float)*(const __fp16*)(mpl + ms*784 + 4*d - 10);
            const float mf1 = (float)*(const __fp16*)(mpl + ms*784 + 4*d - 8);
            const float p0 = s0 * mf0, p1 = s1 * mf1;
            const int slot = rrel & 7;
            *(unsigned*)(ppl  + slot*800 + 4*d) = pkh(p0, p1);
            *(unsigned*)(p2pl + slot*800 + 4*d) = pkh(p0*p0, p1*p1);
        }
    };

    // ---- prologue: constants, pads, qm rels 0..13, p rels 0..3 ----
    for (int dd = tid; dd < 200; dd += NTH) {
        ((unsigned*)ones)[dd] = (dd >= 4 && dd < 196) ? 0x3C003C00u : 0u;
        ((unsigned*)zrow)[dd] = 0u;
    }
    for (int idx = tid; idx < 8*2*11; idx += NTH) {       // p-plane pad dwords
        const int slot = idx / 22, rem = idx % 22;
        const int pl = rem / 11, k = rem % 11;
        const int dd = (k < 4) ? k : (189 + k);           // 0..3, 193..199
        *(unsigned*)((pl ? p2pl : ppl) + slot*800 + 4*dd) = 0u;
    }
    if (tid < 44) rowQ2[tid] = 0.f;
    stage_qm(0, 14);
    __syncthreads();
    stage_p(0);
    __syncthreads();

    // ---- main loop ----
    for (int s = 0; s < NSTR; ++s) {
        const int lr = 4*s + wid;                         // this wave's crop row
        if (lr < nvalid) {
            const int mm    = (m16 < 7) ? m16 : (m16 - 7);
            const int slotA = mod20(lr + mm);
            const char* aB; const char* bB; int j;
            if (m16 < 7)        { aB = qpl + slotA*784; bB = ppl  + (lr & 7)*800; j = m16; }
            else if (m16 < 14)  { aB = mpl + slotA*784; bB = p2pl + (lr & 7)*800; j = m16 - 7; }
            else if (m16 == 14) { aB = ones + 16;       bB = ones;                j = 0; }
            else                { aB = zrow;            bB = zrow;                j = 0; }
            const int Sb = 16 - 2*j + g*16;
            #pragma unroll
            for (int sl = 0; sl < 12; ++sl) {
                const half8 av = *(const half8*)(aB + sl*64 + g*16);
                const int S  = Sb + sl*64;
                const int S0 = S & ~3;
                const unsigned sh = (unsigned)((S & 2) << 3);
                const unsigned* bw = (const unsigned*)(bB + S0);
                const unsigned d0 = bw[0], d1 = bw[1], d2 = bw[2], d3 = bw[3], d4 = bw[4];
                uint4 bi;
                bi.x = __builtin_amdgcn_alignbit(d1, d0, sh);
                bi.y = __builtin_amdgcn_alignbit(d2, d1, sh);
                bi.z = __builtin_amdgcn_alignbit(d3, d2, sh);
                bi.w = __builtin_amdgcn_alignbit(d4, d3, sh);
                const half8 bv = __builtin_bit_cast(half8, bi);
                D = __builtin_amdgcn_mfma_f32_16x16x32_f16(av, bv, D, 0, 0, 0);
            }
        }

        // edges: window rows rel 4s+rr+ei for valid crop rows
        if (tid < 252) {
            #pragma unroll
            for (int rr = 0; rr < 4; ++rr) {
                if (4*s + rr < nvalid) {
                    const int slot = mod20(4*s + rr + ei);
                    const char* pl = (ek == 0) ? mpl : qpl;
                    const float v = (float)*(const __fp16*)(pl + slot*784 + ecolByte);
                    eacc += (ek == 2) ? v*v : v;
                }
            }
        }

        if (s < NSTR - 1) {
            stage_qm(4*s + 14, 4);
            stage_p(4*s + 4);
        }
        __syncthreads();     // single barrier per stripe
    }

    // ---- reduce 4 waves' D, write record ----
    {
        const int rb = (lane >> 4) * 4, col = lane & 15;
        #pragma unroll
        for (int k = 0; k < 4; ++k)
            wred[wid][(rb + k)*16 + col] = D[k];
    }
    __syncthreads();
    float* po = part + (size_t)(b * NGRP + grp) * PSTR;
    po[tid] = wred[0][tid] + wred[1][tid] + wred[2][tid] + wred[3][tid];
    if (tid < 7) {
        float t = 0.f;
        for (int k = 0; k < nvalid; ++k) t += rowQ2[tid + k];
        po[256 + tid] = t;
    }
    if (tid < 252)
        po[264 + ek*84 + ei*12 + et] = eacc;
}

__global__ __launch_bounds__(64)
void mse_kernel(const float* __restrict__ part, double* __restrict__ bmin)
{
    const int b = blockIdx.x;
    const int s = threadIdx.x;           // shifts 0..48 active
    double mse = 1e300;
    if (s < 49) {
        const int i = s / 7, j = s % 7;
        double A=0, Bc=0, Cc=0, Tm=0, Tq=0, Tq2=0, Sp=0;
        double colm[12]={0}, colq[12]={0}, colq2[12]={0};
        for (int gg = 0; gg < NGRP; ++gg) {
            const float* p = part + (size_t)(b * NGRP + gg) * PSTR;
            A   += p[i*16 + j];
            Cc  += p[(7+i)*16 + j];
            Bc  += p[(7+i)*16 + 7 + j];
            Tq  += p[i*16 + 14];
            Tm  += p[(7+i)*16 + 14];
            Sp  += p[14*16 + 0];
            Tq2 += p[256 + i];
            #pragma unroll
            for (int t = 0; t < 12; ++t) {
                colm[t]  += p[264 +      i*12 + t];
                colq[t]  += p[264 + 84 + i*12 + t];
                colq2[t] += p[264 +168 + i*12 + t];
            }
        }
        #pragma unroll
        for (int t = 0; t < 12; ++t) {
            if (t < j || t >= j + 6) {   // col outside x-window [j, j+377]
                Tm -= colm[t]; Tq -= colq[t]; Tq2 -= colq2[t];
            }
        }
        const double bb = (Tq - Sp) / Tm;
        mse = (Tq2 - 2.0*A - 2.0*bb*Tq + Bc + 2.0*bb*Cc + bb*bb*Tm) / Tm;
    }
    for (int off = 32; off; off >>= 1) {
        const double o = __shfl_down(mse, off);
        mse = fmin(mse, o);
    }
    if (s == 0) bmin[b] = mse;
}

__global__ __launch_bounds__(64)
void mean_kernel(const double* __restrict__ bmin, float* __restrict__ out)
{
    double v = bmin[threadIdx.x];
    for (int off = 32; off; off >>= 1) v += __shfl_down(v, off);
    if (threadIdx.x == 0) out[0] = (float)(v / 64.0);
}

extern "C" void kernel_launch(void* const* d_in, const int* in_sizes, int n_in,
                              void* d_out, int out_size, void* d_ws, size_t ws_size,
                              hipStream_t stream) {
    const float* sr = (const float*)d_in[0];
    const float* hr = (const float*)d_in[1];
    const float* mk = (const float*)d_in[2];

    float* part = (float*)d_ws;
    const size_t part_bytes = (size_t)NB * NGRP * PSTR * sizeof(float); // 1597440
    double* bmin = (double*)((char*)d_ws + part_bytes);

    corr_kernel<<<dim3(NB * NGRP), NTH, 0, stream>>>(sr, hr, mk, part);
    mse_kernel<<<dim3(NB), 64, 0, stream>>>(part, bmin);
    mean_kernel<<<dim3(1), 64, 0, stream>>>(bmin, (float*)d_out);
}

// Round 13
// 67.444 us; speedup vs baseline: 2.8039x; 1.0494x over previous
//
#include <hip/hip_runtime.h>

#define IMG   384
#define IMG4  96
#define IMG2  (IMG*IMG)
#define CROP  378
#define NB    64
#define NGRP  12
#define NROWS 32
#define NSTR  8           // stripes of 4 crop rows
#define NTH   256
#define PSTR  520         // 256 D + 8 Tq2 + 252 edges + pad

typedef __fp16 half8  __attribute__((ext_vector_type(8)));
typedef __fp16 f16x2  __attribute__((ext_vector_type(2)));
typedef float  floatx4 __attribute__((ext_vector_type(4)));

__device__ __forceinline__ unsigned pkh(float a, float b) {
    f16x2 h = __builtin_amdgcn_cvt_pkrtz(a, b);
    return __builtin_bit_cast(unsigned, h);
}
__device__ __forceinline__ int mod20(int x) {   // valid for x in [0, 60)
    x -= (x >= 20) ? 20 : 0;
    x -= (x >= 20) ? 20 : 0;
    return x;
}

// MFMA formulation (verified R10/R11): one 16x16x32 f16 MFMA per (crop-row r,
// 32-wide u-slice):
//   A rows 0..6 = q[r+i][u], 7..13 = mask[r+i][u], 14 = ones, 15 = zero
//   B cols 0..6 = p[r][u-j], 7..13 = p^2[r][u-j], 14 = ones, 15 = zero
//   D[i][j]=A, D[7+i][j]=C, D[7+i][7+j]=B, D[i][14]=Tq(i), D[7+i][14]=Tm(i),
//   D[14][0]=Sp.  Tq2(i) from f32 per-row q^2 sums (rowQ2).
// R12: T14 issue-early/write-late staging (loads at stripe top, LDS writes
// after MFMA, single barrier); p-staging mask taken from GLOBAL (removes the
// LDS mask round-trip); two MFMA accumulators (halved dep chain).
// Race safety per stripe s: compute/edge reads q/m rels [4s..4s+9], p slots
// [4s..4s+3]&7; writes q/m rels [4s+14..4s+17] (disjoint mod 20), p rels
// [4s+4..4s+7] (disjoint mod 8).
__global__ __launch_bounds__(NTH)
void corr_kernel(const float* __restrict__ sr, const float* __restrict__ hr,
                 const float* __restrict__ mk, float* __restrict__ part)
{
    __shared__ __align__(16) char qpl [20*784];
    __shared__ __align__(16) char mpl [20*784];
    __shared__ __align__(16) char ppool[2*8*800 + 16];  // p2 staggered +16B
    __shared__ __align__(16) char ones[800];
    __shared__ __align__(16) char zrow[800];
    __shared__ float wred[4][256];
    __shared__ float rowQ2[44];
    char* const ppl  = ppool;
    char* const p2pl = ppool + 8*800 + 16;

    const int tid = threadIdx.x;
    // XCD-clustered: all 12 blocks of a batch on one XCD class
    const int id  = blockIdx.x;
    const int c8  = id & 7;
    const int k0  = id >> 3;              // 0..95
    const int b   = c8 + 8 * (k0 / NGRP);
    const int grp = k0 % NGRP;
    const int c0  = grp * NROWS;
    const int nvalid = (CROP - c0 < NROWS) ? (CROP - c0) : NROWS;

    const float*  sb   = sr + (size_t)b * IMG2;
    const float*  mown = mk + (size_t)b * IMG2;
    const float4* hb4  = (const float4*)(hr + (size_t)b * IMG2);
    const float4* mb4  = (const float4*)(mk + (size_t)b * IMG2);

    const int wid  = tid >> 6;            // 0..3 = row within stripe
    const int lane = tid & 63;
    const int m16  = lane & 15;
    const int g    = lane >> 4;

    floatx4 D0 = {0.f, 0.f, 0.f, 0.f};
    floatx4 D1 = {0.f, 0.f, 0.f, 0.f};

    // edge slot: thread (i, t, kind) accumulates plane value at edge col
    float eacc = 0.f;
    int ei = 0, et = 0, ek = 0, ecolByte = 0;
    if (tid < 252) {
        ei = tid / 36; const int rem = tid % 36; et = rem % 12; ek = rem / 12;
        const int ec = (et < 6) ? et : (372 + et);
        ecolByte = 2 * ec;
    }

    // ---- T14 split staging: issue (global->reg) / write (reg->LDS) ----
    float4 hvr[2], mvr[2];
    auto qm_issue = [&](int relBase) {
        #pragma unroll
        for (int k = 0; k < 2; ++k) {
            const int idx = tid + k * 256;
            if (idx < 384) {
                const int rw = idx / 96, c = idx % 96;
                int w = c0 + relBase + rw; if (w > 383) w = 383;
                hvr[k] = hb4[(size_t)w * IMG4 + c];
                mvr[k] = mb4[(size_t)w * IMG4 + c];
            }
        }
    };
    auto qm_write = [&](int relBase) {
        #pragma unroll
        for (int k = 0; k < 2; ++k) {
            const int idx = tid + k * 256;
            if (idx < 384) {
                const int rw = idx / 96, c = idx % 96;
                const int rel = relBase + rw;
                const float4 hv = hvr[k], mv = mvr[k];
                const float qx = hv.x*mv.x, qy = hv.y*mv.y;
                const float qz = hv.z*mv.z, qw = hv.w*mv.w;
                const int slot = mod20(rel);
                *(uint2*)(qpl + slot*784 + c*8) = make_uint2(pkh(qx, qy), pkh(qz, qw));
                *(uint2*)(mpl + slot*784 + c*8) = make_uint2(pkh(mv.x, mv.y), pkh(mv.z, mv.w));
                atomicAdd(&rowQ2[rel], qx*qx + qy*qy + qz*qz + qw*qw);
            }
        }
    };
    float ps0[3], ps1[3], pm0[3], pm1[3];
    auto p_issue = [&](int relBase) {
        #pragma unroll
        for (int k = 0; k < 3; ++k) {
            const int idx = tid + k * 256;
            if (idx < 756) {
                const int rw = idx / 189, d = 4 + idx % 189;
                int rc = relBase + rw; if (c0 + rc > 377) rc = 377 - c0;
                const int v0 = 2*d - 8;
                const float* srow = sb   + (size_t)(c0 + rc + 3) * IMG + (v0 + 3);
                const float* mrow = mown + (size_t)(c0 + rc + 3) * IMG + (v0 + 3);
                ps0[k] = srow[0]; ps1[k] = srow[1];
                pm0[k] = mrow[0]; pm1[k] = mrow[1];
            }
        }
    };
    auto p_write = [&](int relBase) {
        #pragma unroll
        for (int k = 0; k < 3; ++k) {
            const int idx = tid + k * 256;
            if (idx < 756) {
                const int rw = idx / 189, d = 4 + idx % 189;
                const int rrel = relBase + rw;
                const float p0 = ps0[k] * pm0[k], p1 = ps1[k] * pm1[k];
                const int slot = rrel & 7;
                *(unsigned*)(ppl  + slot*800 + 4*d) = pkh(p0, p1);
                *(unsigned*)(p2pl + slot*800 + 4*d) = pkh(p0*p0, p1*p1);
            }
        }
    };

    // ---- prologue: constants, pads, qm rels 0..13, p rels 0..3 ----
    for (int dd = tid; dd < 200; dd += NTH) {
        ((unsigned*)ones)[dd] = (dd >= 4 && dd < 196) ? 0x3C003C00u : 0u;
        ((unsigned*)zrow)[dd] = 0u;
    }
    for (int idx = tid; idx < 8*2*11; idx += NTH) {       // p-plane pad dwords
        const int slot = idx / 22, rem = idx % 22;
        const int pl = rem / 11, kk = rem % 11;
        const int dd = (kk < 4) ? kk : (189 + kk);        // 0..3, 193..199
        *(unsigned*)((pl ? p2pl : ppl) + slot*800 + 4*dd) = 0u;
    }
    if (tid < 44) rowQ2[tid] = 0.f;
    for (int idx = tid; idx < 14*96; idx += NTH) {        // qm rels 0..13
        const int rw = idx / 96, c = idx % 96;
        int w = c0 + rw; if (w > 383) w = 383;
        const float4 hv = hb4[(size_t)w * IMG4 + c];
        const float4 mv = mb4[(size_t)w * IMG4 + c];
        const float qx = hv.x*mv.x, qy = hv.y*mv.y;
        const float qz = hv.z*mv.z, qw = hv.w*mv.w;
        const int slot = rw;                               // mod20(rw)=rw
        *(uint2*)(qpl + slot*784 + c*8) = make_uint2(pkh(qx, qy), pkh(qz, qw));
        *(uint2*)(mpl + slot*784 + c*8) = make_uint2(pkh(mv.x, mv.y), pkh(mv.z, mv.w));
        atomicAdd(&rowQ2[rw], qx*qx + qy*qy + qz*qz + qw*qw);
    }
    p_issue(0);
    p_write(0);
    __syncthreads();

    // ---- main loop: single barrier per stripe ----
    for (int s = 0; s < NSTR; ++s) {
        const bool doStage = (s < NSTR - 1);
        if (doStage) {                       // issue-early (overlaps MFMA below)
            qm_issue(4*s + 14);
            p_issue(4*s + 4);
        }

        const int lr = 4*s + wid;            // this wave's crop row
        if (lr < nvalid) {
            const int mm    = (m16 < 7) ? m16 : (m16 - 7);
            const int slotA = mod20(lr + mm);
            const char* aB; const char* bB; int j;
            if (m16 < 7)        { aB = qpl + slotA*784; bB = ppl  + (lr & 7)*800; j = m16; }
            else if (m16 < 14)  { aB = mpl + slotA*784; bB = p2pl + (lr & 7)*800; j = m16 - 7; }
            else if (m16 == 14) { aB = ones + 16;       bB = ones;                j = 0; }
            else                { aB = zrow;            bB = zrow;                j = 0; }
            const int Sb = 16 - 2*j + g*16;
            #pragma unroll
            for (int sl = 0; sl < 12; ++sl) {
                const half8 av = *(const half8*)(aB + sl*64 + g*16);
                const int S  = Sb + sl*64;
                const int S0 = S & ~3;
                const unsigned sh = (unsigned)((S & 2) << 3);
                const unsigned* bw = (const unsigned*)(bB + S0);
                const unsigned d0 = bw[0], d1 = bw[1], d2 = bw[2], d3 = bw[3], d4 = bw[4];
                uint4 bi;
                bi.x = __builtin_amdgcn_alignbit(d1, d0, sh);
                bi.y = __builtin_amdgcn_alignbit(d2, d1, sh);
                bi.z = __builtin_amdgcn_alignbit(d3, d2, sh);
                bi.w = __builtin_amdgcn_alignbit(d4, d3, sh);
                const half8 bv = __builtin_bit_cast(half8, bi);
                if (sl & 1) D1 = __builtin_amdgcn_mfma_f32_16x16x32_f16(av, bv, D1, 0, 0, 0);
                else        D0 = __builtin_amdgcn_mfma_f32_16x16x32_f16(av, bv, D0, 0, 0, 0);
            }
        }

        // edges: window rows rel 4s+rr+ei for valid crop rows
        if (tid < 252) {
            #pragma unroll
            for (int rr = 0; rr < 4; ++rr) {
                if (4*s + rr < nvalid) {
                    const int slot = mod20(4*s + rr + ei);
                    const char* pl = (ek == 0) ? mpl : qpl;
                    const float v = (float)*(const __fp16*)(pl + slot*784 + ecolByte);
                    eacc += (ek == 2) ? v*v : v;
                }
            }
        }

        if (doStage) {                       // write-late
            qm_write(4*s + 14);
            p_write(4*s + 4);
        }
        __syncthreads();
    }

    // ---- reduce 4 waves' D, write record ----
    {
        const floatx4 D = D0 + D1;
        const int rb = (lane >> 4) * 4, col = lane & 15;
        #pragma unroll
        for (int k = 0; k < 4; ++k)
            wred[wid][(rb + k)*16 + col] = D[k];
    }
    __syncthreads();
    float* po = part + (size_t)(b * NGRP + grp) * PSTR;
    po[tid] = wred[0][tid] + wred[1][tid] + wred[2][tid] + wred[3][tid];
    if (tid < 7) {
        float t = 0.f;
        for (int k = 0; k < nvalid; ++k) t += rowQ2[tid + k];
        po[256 + tid] = t;
    }
    if (tid < 252)
        po[264 + ek*84 + ei*12 + et] = eacc;
}

__global__ __launch_bounds__(64)
void mse_kernel(const float* __restrict__ part, double* __restrict__ bmin)
{
    const int b = blockIdx.x;
    const int s = threadIdx.x;           // shifts 0..48 active
    double mse = 1e300;
    if (s < 49) {
        const int i = s / 7, j = s % 7;
        double A=0, Bc=0, Cc=0, Tm=0, Tq=0, Tq2=0, Sp=0;
        double colm[12]={0}, colq[12]={0}, colq2[12]={0};
        for (int gg = 0; gg < NGRP; ++gg) {
            const float* p = part + (size_t)(b * NGRP + gg) * PSTR;
            A   += p[i*16 + j];
            Cc  += p[(7+i)*16 + j];
            Bc  += p[(7+i)*16 + 7 + j];
            Tq  += p[i*16 + 14];
            Tm  += p[(7+i)*16 + 14];
            Sp  += p[14*16 + 0];
            Tq2 += p[256 + i];
            #pragma unroll
            for (int t = 0; t < 12; ++t) {
                colm[t]  += p[264 +      i*12 + t];
                colq[t]  += p[264 + 84 + i*12 + t];
                colq2[t] += p[264 +168 + i*12 + t];
            }
        }
        #pragma unroll
        for (int t = 0; t < 12; ++t) {
            if (t < j || t >= j + 6) {   // col outside x-window [j, j+377]
                Tm -= colm[t]; Tq -= colq[t]; Tq2 -= colq2[t];
            }
        }
        const double bb = (Tq - Sp) / Tm;
        mse = (Tq2 - 2.0*A - 2.0*bb*Tq + Bc + 2.0*bb*Cc + bb*bb*Tm) / Tm;
    }
    for (int off = 32; off; off >>= 1) {
        const double o = __shfl_down(mse, off);
        mse = fmin(mse, o);
    }
    if (s == 0) bmin[b] = mse;
}

__global__ __launch_bounds__(64)
void mean_kernel(const double* __restrict__ bmin, float* __restrict__ out)
{
    double v = bmin[threadIdx.x];
    for (int off = 32; off; off >>= 1) v += __shfl_down(v, off);
    if (threadIdx.x == 0) out[0] = (float)(v / 64.0);
}

extern "C" void kernel_launch(void* const* d_in, const int* in_sizes, int n_in,
                              void* d_out, int out_size, void* d_ws, size_t ws_size,
                              hipStream_t stream) {
    const float* sr = (const float*)d_in[0];
    const float* hr = (const float*)d_in[1];
    const float* mk = (const float*)d_in[2];

    float* part = (float*)d_ws;
    const size_t part_bytes = (size_t)NB * NGRP * PSTR * sizeof(float); // 1597440
    double* bmin = (double*)((char*)d_ws + part_bytes);

    corr_kernel<<<dim3(NB * NGRP), NTH, 0, stream>>>(sr, hr, mk, part);
    mse_kernel<<<dim3(NB), 64, 0, stream>>>(part, bmin);
    mean_kernel<<<dim3(1), 64, 0, stream>>>(bmin, (float*)d_out);
}